// Round 3
// baseline (901.396 us; speedup 1.0000x reference)
//
#include <hip/hip_runtime.h>

// Problem constants (from reference): B=2, L=2048, D=1024, H=16, DK=64
#define B_  2
#define L_  2048
#define D_  1024
#define H_  16
#define DK_ 64
#define SCALE_ 0.35355339059327373f   // 64^-0.25

typedef _Float16 f16;
typedef __attribute__((ext_vector_type(8))) _Float16 f16x8;
typedef __attribute__((ext_vector_type(4))) _Float16 f16x4;
typedef __attribute__((ext_vector_type(4))) float    f32x4;

#define AS1C(p) ((const __attribute__((address_space(1))) void*)(p))
#define AS3(p)  ((__attribute__((address_space(3))) void*)(p))

// ---------------------------------------------------------------------------
// fp32 -> fp16 conversion, batched over blockIdx.z (memory-bound, 4 elems/thr)
// ---------------------------------------------------------------------------
struct CvtArgs { const float* in[4]; f16* out[4]; };

__global__ void cvt_f32_f16(CvtArgs a, int n) {
    const int z = blockIdx.z;
    const float* __restrict__ in = a.in[z];
    f16* __restrict__ out = a.out[z];
    int i = (blockIdx.x * blockDim.x + threadIdx.x) * 4;
    if (i < n) {
        float4 v = *(const float4*)&in[i];
        f16x4 o;
        o[0] = (f16)v.x; o[1] = (f16)v.y; o[2] = (f16)v.z; o[3] = (f16)v.w;
        *(f16x4*)&out[i] = o;
    }
}

// ---------------------------------------------------------------------------
// GEMM: C[M,N] = alpha * A[M,K] @ B[N,K]^T   (both row-major, K contig)
// 128x128 tile, BK=32, global_load_lds width 16, mfma 16x16x32 f16.
// T3+T4: 3-buffer ring, 2-deep prefetch, counted vmcnt so the next tile's 4
// loads stay in flight ACROSS the barrier (never drained to 0 mid-loop).
// One s_barrier per K-step. Safety: explicit lgkmcnt(0) before the barrier
// guarantees all LDS reads complete before any wave can restage that buffer
// (stage targets the buffer last read at iter t-1, fenced after the barrier).
// ---------------------------------------------------------------------------
template <typename OutT>
__device__ __forceinline__ void gemm_bt_body(
    const f16* __restrict__ A, const f16* __restrict__ Bm, OutT* __restrict__ C,
    int M, int N, int Kd, float alpha)
{
    __shared__ f16 As[3][128 * 32];
    __shared__ f16 Bs[3][128 * 32];

    const int tid  = threadIdx.x;
    const int lane = tid & 63;
    const int w    = tid >> 6;
    const int quad = lane >> 4;
    const int l16  = lane & 15;
    const int wm   = w & 1, wn = w >> 1;
    const int m0   = blockIdx.y * 128;
    const int n0   = blockIdx.x * 128;

    f32x4 acc[4][4] = {};
    const int nt = Kd >> 5;   // 32-wide K steps

    // stage tile t into buffer buf: 128 rows x 32 halfs, 512 chunks of 16 B;
    // 4 global_load_lds instructions per wave (vmcnt +4 per stage)
    auto stage = [&](int t, int buf) {
        const int k0 = t * 32;
#pragma unroll
        for (int it = 0; it < 2; ++it) {
            int cc   = tid + it * 256;
            int row  = cc >> 2;
            int koff = (cc & 3) * 8;   // halfs
            __builtin_amdgcn_global_load_lds(AS1C(&A[(size_t)(m0 + row) * Kd + k0 + koff]),
                                             AS3(&As[buf][cc * 8]), 16, 0, 0);
            __builtin_amdgcn_global_load_lds(AS1C(&Bm[(size_t)(n0 + row) * Kd + k0 + koff]),
                                             AS3(&Bs[buf][cc * 8]), 16, 0, 0);
        }
    };

    stage(0, 0);              // vmcnt 4
    if (nt > 1) stage(1, 1);  // vmcnt 8
    int cur = 0;

    for (int t = 0; t < nt; ++t) {
        asm volatile("" ::: "memory");                      // no mem op crosses down
        asm volatile("s_waitcnt lgkmcnt(0)" ::: "memory");  // my LDS reads complete (WAR)
        if (t + 1 < nt) {
            asm volatile("s_waitcnt vmcnt(4)" ::: "memory");  // tile t landed; t+1 in flight
        } else {
            asm volatile("s_waitcnt vmcnt(0)" ::: "memory");  // last tile: full drain
        }
        __builtin_amdgcn_s_barrier();                       // tile t resident block-wide
        asm volatile("" ::: "memory");                      // no mem op crosses up

        // restage the buffer last read at iter t-1 (all reads done: lgkm+barrier)
        if (t + 2 < nt) stage(t + 2, (t + 2) % 3);

        f16x8 af[4], bf[4];
#pragma unroll
        for (int i = 0; i < 4; ++i) {
            af[i] = *(const f16x8*)&As[cur][(wm * 64 + i * 16 + l16) * 32 + quad * 8];
            bf[i] = *(const f16x8*)&Bs[cur][(wn * 64 + i * 16 + l16) * 32 + quad * 8];
        }
        __builtin_amdgcn_s_setprio(1);
#pragma unroll
        for (int i = 0; i < 4; ++i)
#pragma unroll
            for (int j = 0; j < 4; ++j)
                acc[i][j] = __builtin_amdgcn_mfma_f32_16x16x32_f16(af[i], bf[j], acc[i][j], 0, 0, 0);
        __builtin_amdgcn_s_setprio(0);

        cur = (cur + 1 == 3) ? 0 : cur + 1;
    }

    // epilogue: C/D layout col = lane&15, row = quad*4 + reg
#pragma unroll
    for (int i = 0; i < 4; ++i)
#pragma unroll
        for (int j = 0; j < 4; ++j)
#pragma unroll
            for (int r = 0; r < 4; ++r) {
                int row = m0 + wm * 64 + i * 16 + quad * 4 + r;
                int col = n0 + wn * 64 + j * 16 + l16;
                C[(size_t)row * N + col] = (OutT)(acc[i][j][r] * alpha);
            }
}

// batched projection GEMM: z selects (input, weight, output, alpha)
struct ProjArgs {
    const f16* A[3];
    const f16* Bm[3];
    f16*       C[3];
    float      alpha[3];
};

__global__ __launch_bounds__(256) void gemm_proj3(ProjArgs p, int M, int N, int Kd) {
    const int z = blockIdx.z;
    gemm_bt_body<f16>(p.A[z], p.Bm[z], p.C[z], M, N, Kd, p.alpha[z]);
}

__global__ __launch_bounds__(256) void gemm_out(
    const f16* __restrict__ A, const f16* __restrict__ Bm, float* __restrict__ C,
    int M, int N, int Kd, float alpha) {
    gemm_bt_body<float>(A, Bm, C, M, N, Kd, alpha);
}

// ---------------------------------------------------------------------------
// Flash attention: per block = (b, h, 64-row Q tile); 4 waves x 16 Q-rows.
// Q,K pre-scaled by SCALE in the projection GEMMs. posbias added in fp32.
// T14: V global loads issued at top of iteration; VT transpose LDS-writes
// deferred to just before the barrier (V latency hides under QK^T+softmax).
// VT double-buffered -> ONE __syncthreads per KV-tile (was 2): iter t+1
// writes VT[b^1], whose last readers (iter t-1) completed before passing the
// iter-t barrier (lgkm drained by __syncthreads).
// T5: setprio(1) around both MFMA clusters.
// ---------------------------------------------------------------------------
__global__ __launch_bounds__(256) void attn_kernel(
    const f16* __restrict__ Q, const f16* __restrict__ K, const f16* __restrict__ V,
    const float* __restrict__ bias, f16* __restrict__ ctx)
{
    const int qt = blockIdx.x & 31;          // L/64 = 32 q-tiles
    const int h  = (blockIdx.x >> 5) & 15;
    const int b  = blockIdx.x >> 9;
    const int q0 = qt * 64;

    const int tid  = threadIdx.x;
    const int w    = tid >> 6;
    const int lane = tid & 63;
    const int quad = lane >> 4;
    const int l16  = lane & 15;

    __shared__ f16 VT[2][64][72];            // V^T tile, double-buffered, +8 pad
    __shared__ f16 P[4][16][72];             // per-wave P tile (no cross-wave use)

    const size_t bh = (size_t)b * L_ * D_ + (size_t)h * DK_;

    // Q fragments for this wave's 16 rows (held in regs for whole block)
    f16x8 qf[2];
    {
        const size_t qrow = (size_t)(q0 + w * 16 + l16);
#pragma unroll
        for (int ks = 0; ks < 2; ++ks)
            qf[ks] = *(const f16x8*)&Q[bh + qrow * D_ + ks * 32 + quad * 8];
    }

    f32x4 oacc[4] = {};                      // 4 n-groups (DK cols) x 4 rows
    float m_r[4], l_r[4];
#pragma unroll
    for (int r = 0; r < 4; ++r) { m_r[r] = -1e30f; l_r[r] = 0.f; }

    const float* biasrow = bias + ((size_t)(b * H_ + h) * L_ + q0 + w * 16) * L_;

    const int vr  = tid >> 2;
    const int vc0 = (tid & 3) * 16;

    int vb = 0;
    for (int j0 = 0; j0 < L_; j0 += 64, vb ^= 1) {
        // ---- T14 issue-early: V tile global loads (coalesced 16B) ----
        f16x8 v0 = *(const f16x8*)&V[bh + (size_t)(j0 + vr) * D_ + vc0];
        f16x8 v1 = *(const f16x8*)&V[bh + (size_t)(j0 + vr) * D_ + vc0 + 8];

        // ---- S = Q K^T (16x64 per wave), direct global K frags ----
        f32x4 s[4];
        __builtin_amdgcn_s_setprio(1);
#pragma unroll
        for (int g = 0; g < 4; ++g) {
            const size_t krow = (size_t)(j0 + g * 16 + l16);
            f16x8 kf0 = *(const f16x8*)&K[bh + krow * D_ + quad * 8];
            f16x8 kf1 = *(const f16x8*)&K[bh + krow * D_ + 32 + quad * 8];
            f32x4 a = {};
            a = __builtin_amdgcn_mfma_f32_16x16x32_f16(qf[0], kf0, a, 0, 0, 0);
            a = __builtin_amdgcn_mfma_f32_16x16x32_f16(qf[1], kf1, a, 0, 0, 0);
            s[g] = a;
        }
        __builtin_amdgcn_s_setprio(0);

        // ---- + posbias (fp32) ----
#pragma unroll
        for (int g = 0; g < 4; ++g)
#pragma unroll
            for (int r = 0; r < 4; ++r)
                s[g][r] += biasrow[(size_t)(quad * 4 + r) * L_ + j0 + g * 16 + l16];

        // ---- online softmax (rows live in 16-lane groups: row = quad*4+reg) ----
        float alpha[4];
#pragma unroll
        for (int r = 0; r < 4; ++r) {
            float mx = fmaxf(fmaxf(s[0][r], s[1][r]), fmaxf(s[2][r], s[3][r]));
#pragma unroll
            for (int off = 1; off < 16; off <<= 1)
                mx = fmaxf(mx, __shfl_xor(mx, off, 64));
            float mi = fmaxf(m_r[r], mx);
            alpha[r] = __expf(m_r[r] - mi);
            m_r[r]   = mi;
        }
#pragma unroll
        for (int g = 0; g < 4; ++g)
#pragma unroll
            for (int r = 0; r < 4; ++r)
                s[g][r] = __expf(s[g][r] - m_r[r]);
#pragma unroll
        for (int r = 0; r < 4; ++r) {
            float sm = s[0][r] + s[1][r] + s[2][r] + s[3][r];
#pragma unroll
            for (int off = 1; off < 16; off <<= 1)
                sm += __shfl_xor(sm, off, 64);
            l_r[r] = l_r[r] * alpha[r] + sm;
        }
#pragma unroll
        for (int g = 0; g < 4; ++g)
#pragma unroll
            for (int r = 0; r < 4; ++r)
                oacc[g][r] *= alpha[r];

        // ---- P (fp16) -> LDS in C-layout; read back in A-layout ----
#pragma unroll
        for (int g = 0; g < 4; ++g)
#pragma unroll
            for (int r = 0; r < 4; ++r)
                P[w][quad * 4 + r][g * 16 + l16] = (f16)s[g][r];

        // ---- T14 write-late: VT transpose stores (loads long since landed) ----
#pragma unroll
        for (int i = 0; i < 8; ++i) {
            VT[vb][vc0 + i][vr]     = v0[i];
            VT[vb][vc0 + 8 + i][vr] = v1[i];
        }

        __syncthreads();   // the ONLY barrier: VT[vb] staged block-wide

        // ---- O += P V ----
        __builtin_amdgcn_s_setprio(1);
#pragma unroll
        for (int ks = 0; ks < 2; ++ks) {
            f16x8 pf = *(const f16x8*)&P[w][l16][ks * 32 + quad * 8];
#pragma unroll
            for (int g = 0; g < 4; ++g) {
                f16x8 vf = *(const f16x8*)&VT[vb][g * 16 + l16][ks * 32 + quad * 8];
                oacc[g] = __builtin_amdgcn_mfma_f32_16x16x32_f16(pf, vf, oacc[g], 0, 0, 0);
            }
        }
        __builtin_amdgcn_s_setprio(0);
        // no second barrier: next iter writes VT[vb^1], last read at iter-1,
        // whose readers all passed this iteration's __syncthreads.
    }

    // ---- epilogue: ctx[b, q, h*DK + c] = O / l ----
#pragma unroll
    for (int g = 0; g < 4; ++g)
#pragma unroll
        for (int r = 0; r < 4; ++r) {
            size_t row = (size_t)(q0 + w * 16 + quad * 4 + r);
            ctx[(size_t)b * L_ * D_ + row * D_ + h * DK_ + g * 16 + l16] =
                (f16)(oacc[g][r] / l_r[r]);
        }
}

// ---------------------------------------------------------------------------
// launcher
// ---------------------------------------------------------------------------
extern "C" void kernel_launch(void* const* d_in, const int* in_sizes, int n_in,
                              void* d_out, int out_size, void* d_ws, size_t ws_size,
                              hipStream_t stream)
{
    const float* query = (const float*)d_in[0];
    const float* key   = (const float*)d_in[1];
    const float* value = (const float*)d_in[2];
    const float* pbias = (const float*)d_in[3];
    const float* Wq    = (const float*)d_in[4];
    const float* Wk    = (const float*)d_in[5];
    const float* Wv    = (const float*)d_in[6];
    const float* Wo    = (const float*)d_in[7];
    float* out = (float*)d_out;

    char* ws = (char*)d_ws;
    // workspace layout (needs 64 MiB)
    f16* q16  = (f16*)(ws + 0);           // 4096x1024 halfs = 8 MiB each
    f16* k16  = (f16*)(ws + 8388608);
    f16* v16  = (f16*)(ws + 16777216);
    f16* wq16 = (f16*)(ws + 25165824);    // 1024x1024 halfs = 2 MiB each
    f16* wk16 = (f16*)(ws + 27262976);
    f16* wv16 = (f16*)(ws + 29360128);
    f16* wo16 = (f16*)(ws + 31457280);
    f16* Qs   = (f16*)(ws + 33554432);
    f16* Ks   = (f16*)(ws + 41943040);
    f16* Vs   = (f16*)(ws + 50331648);
    f16* ctx  = (f16*)(ws + 58720256);

    const int ML = B_ * L_;               // 4096
    const int nBig = ML * D_;             // 4,194,304
    const int nW   = D_ * D_;             // 1,048,576

    // batched fp32->fp16 converts: {q,k,v} then {Wq,Wk,Wv,Wo}
    {
        CvtArgs a{};
        a.in[0] = query; a.in[1] = key; a.in[2] = value;
        a.out[0] = q16;  a.out[1] = k16; a.out[2] = v16;
        cvt_f32_f16<<<dim3((nBig / 4 + 255) / 256, 1, 3), 256, 0, stream>>>(a, nBig);
    }
    {
        CvtArgs a{};
        a.in[0] = Wq;   a.in[1] = Wk;   a.in[2] = Wv;   a.in[3] = Wo;
        a.out[0] = wq16; a.out[1] = wk16; a.out[2] = wv16; a.out[3] = wo16;
        cvt_f32_f16<<<dim3((nW / 4 + 255) / 256, 1, 4), 256, 0, stream>>>(a, nW);
    }

    // batched Q/K/V projections: 768 blocks = 3 co-resident blocks/CU
    {
        ProjArgs p{};
        p.A[0] = q16;  p.A[1] = k16;  p.A[2] = v16;
        p.Bm[0] = wq16; p.Bm[1] = wk16; p.Bm[2] = wv16;
        p.C[0] = Qs;   p.C[1] = Ks;   p.C[2] = Vs;
        p.alpha[0] = SCALE_; p.alpha[1] = SCALE_; p.alpha[2] = 1.0f;
        gemm_proj3<<<dim3(D_ / 128, ML / 128, 3), 256, 0, stream>>>(p, ML, D_, D_);
    }

    attn_kernel<<<dim3(B_ * H_ * (L_ / 64)), 256, 0, stream>>>(Qs, Ks, Vs, pbias, ctx);

    gemm_out<<<dim3(D_ / 128, ML / 128), 256, 0, stream>>>(ctx, wo16, out, ML, D_, D_, 1.0f);
}

// Round 4
// 892.660 us; speedup vs baseline: 1.0098x; 1.0098x over previous
//
#include <hip/hip_runtime.h>

// Problem constants (from reference): B=2, L=2048, D=1024, H=16, DK=64
#define B_  2
#define L_  2048
#define D_  1024
#define H_  16
#define DK_ 64
#define SCALE_ 0.35355339059327373f   // 64^-0.25

typedef _Float16 f16;
typedef __attribute__((ext_vector_type(8))) _Float16 f16x8;
typedef __attribute__((ext_vector_type(4))) _Float16 f16x4;
typedef __attribute__((ext_vector_type(4))) float    f32x4;

#define AS1C(p) ((const __attribute__((address_space(1))) void*)(p))
#define AS3(p)  ((__attribute__((address_space(3))) void*)(p))

// ---------------------------------------------------------------------------
// fp32 -> fp16 conversion, batched over blockIdx.z (memory-bound, 4 elems/thr)
// ---------------------------------------------------------------------------
struct CvtArgs { const float* in[4]; f16* out[4]; };

__global__ void cvt_f32_f16(CvtArgs a, int n) {
    const int z = blockIdx.z;
    const float* __restrict__ in = a.in[z];
    f16* __restrict__ out = a.out[z];
    int i = (blockIdx.x * blockDim.x + threadIdx.x) * 4;
    if (i < n) {
        float4 v = *(const float4*)&in[i];
        f16x4 o;
        o[0] = (f16)v.x; o[1] = (f16)v.y; o[2] = (f16)v.z; o[3] = (f16)v.w;
        *(f16x4*)&out[i] = o;
    }
}

// ---------------------------------------------------------------------------
// GEMM: C[M,N] = alpha * A[M,K] @ B[N,K]^T   (both row-major, K contig)
// 128x128 tile, BK=32, global_load_lds width 16, mfma 16x16x32 f16.
// T3+T4: 3-buffer ring, 2-deep prefetch, counted vmcnt (frozen since R3;
// verified correct, perf-neutral vs 2-phase -> GEMMs are not the bottleneck).
// ---------------------------------------------------------------------------
template <typename OutT>
__device__ __forceinline__ void gemm_bt_body(
    const f16* __restrict__ A, const f16* __restrict__ Bm, OutT* __restrict__ C,
    int M, int N, int Kd, float alpha)
{
    __shared__ f16 As[3][128 * 32];
    __shared__ f16 Bs[3][128 * 32];

    const int tid  = threadIdx.x;
    const int lane = tid & 63;
    const int w    = tid >> 6;
    const int quad = lane >> 4;
    const int l16  = lane & 15;
    const int wm   = w & 1, wn = w >> 1;
    const int m0   = blockIdx.y * 128;
    const int n0   = blockIdx.x * 128;

    f32x4 acc[4][4] = {};
    const int nt = Kd >> 5;   // 32-wide K steps

    auto stage = [&](int t, int buf) {
        const int k0 = t * 32;
#pragma unroll
        for (int it = 0; it < 2; ++it) {
            int cc   = tid + it * 256;
            int row  = cc >> 2;
            int koff = (cc & 3) * 8;   // halfs
            __builtin_amdgcn_global_load_lds(AS1C(&A[(size_t)(m0 + row) * Kd + k0 + koff]),
                                             AS3(&As[buf][cc * 8]), 16, 0, 0);
            __builtin_amdgcn_global_load_lds(AS1C(&Bm[(size_t)(n0 + row) * Kd + k0 + koff]),
                                             AS3(&Bs[buf][cc * 8]), 16, 0, 0);
        }
    };

    stage(0, 0);              // vmcnt 4
    if (nt > 1) stage(1, 1);  // vmcnt 8
    int cur = 0;

    for (int t = 0; t < nt; ++t) {
        asm volatile("" ::: "memory");
        asm volatile("s_waitcnt lgkmcnt(0)" ::: "memory");  // my LDS reads complete (WAR)
        if (t + 1 < nt) {
            asm volatile("s_waitcnt vmcnt(4)" ::: "memory");  // tile t landed; t+1 in flight
        } else {
            asm volatile("s_waitcnt vmcnt(0)" ::: "memory");
        }
        __builtin_amdgcn_s_barrier();
        asm volatile("" ::: "memory");

        if (t + 2 < nt) stage(t + 2, (t + 2) % 3);

        f16x8 af[4], bf[4];
#pragma unroll
        for (int i = 0; i < 4; ++i) {
            af[i] = *(const f16x8*)&As[cur][(wm * 64 + i * 16 + l16) * 32 + quad * 8];
            bf[i] = *(const f16x8*)&Bs[cur][(wn * 64 + i * 16 + l16) * 32 + quad * 8];
        }
        __builtin_amdgcn_s_setprio(1);
#pragma unroll
        for (int i = 0; i < 4; ++i)
#pragma unroll
            for (int j = 0; j < 4; ++j)
                acc[i][j] = __builtin_amdgcn_mfma_f32_16x16x32_f16(af[i], bf[j], acc[i][j], 0, 0, 0);
        __builtin_amdgcn_s_setprio(0);

        cur = (cur + 1 == 3) ? 0 : cur + 1;
    }

    // epilogue: C/D layout col = lane&15, row = quad*4 + reg
#pragma unroll
    for (int i = 0; i < 4; ++i)
#pragma unroll
        for (int j = 0; j < 4; ++j)
#pragma unroll
            for (int r = 0; r < 4; ++r) {
                int row = m0 + wm * 64 + i * 16 + quad * 4 + r;
                int col = n0 + wn * 64 + j * 16 + l16;
                C[(size_t)row * N + col] = (OutT)(acc[i][j][r] * alpha);
            }
}

// batched projection GEMM: z selects (input, weight, output, alpha)
struct ProjArgs {
    const f16* A[3];
    const f16* Bm[3];
    f16*       C[3];
    float      alpha[3];
};

__global__ __launch_bounds__(256) void gemm_proj3(ProjArgs p, int M, int N, int Kd) {
    const int z = blockIdx.z;
    gemm_bt_body<f16>(p.A[z], p.Bm[z], p.C[z], M, N, Kd, p.alpha[z]);
}

__global__ __launch_bounds__(256) void gemm_out(
    const f16* __restrict__ A, const f16* __restrict__ Bm, float* __restrict__ C,
    int M, int N, int Kd, float alpha) {
    gemm_bt_body<float>(A, Bm, C, M, N, Kd, alpha);
}

// ---------------------------------------------------------------------------
// Flash attention: per block = (b, h, 64-row Q tile); 4 waves x 16 Q-rows.
// Q,K pre-scaled by SCALE in the projection GEMMs. posbias added in fp32.
//
// R4 changes:
//  * VT XOR swizzle (physical col = col ^ (((row>>4)&3)<<4)): the transpose
//    write previously hit rows {i,i+16,i+32,i+48} per instruction, which are
//    576 dwords apart == same bank (8-way conflict on 16 ds_write_b16/lane).
//    The swizzle maps the 4 row-groups to 4 disjoint 16-col ranges -> all 32
//    banks, 2 lanes/dword (free). Read side: key = g<<4, constant per
//    fragment; XOR bits >= 16 preserve 16B contiguity -> ds_read_b128 banks
//    unchanged (2-way, free).
//  * Load-order pipeline: per tile issue K frags (8) -> V (2) -> bias (16,
//    nontemporal) BEFORE the QK^T cluster. vmcnt is FIFO: waiting on K for
//    the MFMAs leaves V+bias in flight under QK^T; bias lands by its use.
//    nontemporal keeps the 537 MB zero-reuse bias stream from evicting the
//    K/V working set (512 KB/(b,h), reused by 32 blocks) in L2.
//  * T5 setprio around MFMA clusters; single __syncthreads per KV tile
//    (VT double-buffered).
// ---------------------------------------------------------------------------
__global__ __launch_bounds__(256) void attn_kernel(
    const f16* __restrict__ Q, const f16* __restrict__ K, const f16* __restrict__ V,
    const float* __restrict__ bias, f16* __restrict__ ctx)
{
    const int qt = blockIdx.x & 31;          // L/64 = 32 q-tiles
    const int h  = (blockIdx.x >> 5) & 15;
    const int b  = blockIdx.x >> 9;
    const int q0 = qt * 64;

    const int tid  = threadIdx.x;
    const int w    = tid >> 6;
    const int lane = tid & 63;
    const int quad = lane >> 4;
    const int l16  = lane & 15;

    __shared__ f16 VT[2][64][72];            // V^T tile, double-buffered, +8 pad
    __shared__ f16 P[4][16][72];             // per-wave P tile (no cross-wave use)

    const size_t bh = (size_t)b * L_ * D_ + (size_t)h * DK_;

    // Q fragments for this wave's 16 rows (held in regs for whole block)
    f16x8 qf[2];
    {
        const size_t qrow = (size_t)(q0 + w * 16 + l16);
#pragma unroll
        for (int ks = 0; ks < 2; ++ks)
            qf[ks] = *(const f16x8*)&Q[bh + qrow * D_ + ks * 32 + quad * 8];
    }

    f32x4 oacc[4] = {};                      // 4 n-groups (DK cols) x 4 rows
    float m_r[4], l_r[4];
#pragma unroll
    for (int r = 0; r < 4; ++r) { m_r[r] = -1e30f; l_r[r] = 0.f; }

    const float* biasrow = bias + ((size_t)(b * H_ + h) * L_ + q0 + w * 16) * L_;

    const int vr   = tid >> 2;
    const int vc0  = (tid & 3) * 16;
    const int vkey = (vc0 >> 4) << 4;        // VT write swizzle key (row>>4&3)<<4

    int vb = 0;
    for (int j0 = 0; j0 < L_; j0 += 64, vb ^= 1) {
        // ---- issue ALL loads first: K (oldest; MFMAs wait only on these),
        //      then V, then bias (youngest; stay in flight under QK^T) ----
        f16x8 kf[4][2];
#pragma unroll
        for (int g = 0; g < 4; ++g) {
            const size_t krow = (size_t)(j0 + g * 16 + l16);
            kf[g][0] = *(const f16x8*)&K[bh + krow * D_ + quad * 8];
            kf[g][1] = *(const f16x8*)&K[bh + krow * D_ + 32 + quad * 8];
        }
        f16x8 v0 = *(const f16x8*)&V[bh + (size_t)(j0 + vr) * D_ + vc0];
        f16x8 v1 = *(const f16x8*)&V[bh + (size_t)(j0 + vr) * D_ + vc0 + 8];
        float bpre[16];
#pragma unroll
        for (int g = 0; g < 4; ++g)
#pragma unroll
            for (int r = 0; r < 4; ++r)
                bpre[g * 4 + r] = __builtin_nontemporal_load(
                    &biasrow[(size_t)(quad * 4 + r) * L_ + j0 + g * 16 + l16]);

        // ---- S = Q K^T (16x64 per wave) ----
        f32x4 s[4];
        __builtin_amdgcn_s_setprio(1);
#pragma unroll
        for (int g = 0; g < 4; ++g) {
            f32x4 a = {};
            a = __builtin_amdgcn_mfma_f32_16x16x32_f16(qf[0], kf[g][0], a, 0, 0, 0);
            a = __builtin_amdgcn_mfma_f32_16x16x32_f16(qf[1], kf[g][1], a, 0, 0, 0);
            s[g] = a;
        }
        __builtin_amdgcn_s_setprio(0);

        // ---- + posbias (fp32, prefetched) ----
#pragma unroll
        for (int g = 0; g < 4; ++g)
#pragma unroll
            for (int r = 0; r < 4; ++r)
                s[g][r] += bpre[g * 4 + r];

        // ---- online softmax (rows live in 16-lane groups: row = quad*4+reg) ----
        float alpha[4];
#pragma unroll
        for (int r = 0; r < 4; ++r) {
            float mx = fmaxf(fmaxf(s[0][r], s[1][r]), fmaxf(s[2][r], s[3][r]));
#pragma unroll
            for (int off = 1; off < 16; off <<= 1)
                mx = fmaxf(mx, __shfl_xor(mx, off, 64));
            float mi = fmaxf(m_r[r], mx);
            alpha[r] = __expf(m_r[r] - mi);
            m_r[r]   = mi;
        }
#pragma unroll
        for (int g = 0; g < 4; ++g)
#pragma unroll
            for (int r = 0; r < 4; ++r)
                s[g][r] = __expf(s[g][r] - m_r[r]);
#pragma unroll
        for (int r = 0; r < 4; ++r) {
            float sm = s[0][r] + s[1][r] + s[2][r] + s[3][r];
#pragma unroll
            for (int off = 1; off < 16; off <<= 1)
                sm += __shfl_xor(sm, off, 64);
            l_r[r] = l_r[r] * alpha[r] + sm;
        }
#pragma unroll
        for (int g = 0; g < 4; ++g)
#pragma unroll
            for (int r = 0; r < 4; ++r)
                oacc[g][r] *= alpha[r];

        // ---- P (fp16) -> LDS in C-layout; read back in A-layout ----
#pragma unroll
        for (int g = 0; g < 4; ++g)
#pragma unroll
            for (int r = 0; r < 4; ++r)
                P[w][quad * 4 + r][g * 16 + l16] = (f16)s[g][r];

        // ---- VT transpose stores, XOR-swizzled (conflict-free) ----
#pragma unroll
        for (int i = 0; i < 8; ++i) {
            VT[vb][vc0 + i][vr ^ vkey]     = v0[i];
            VT[vb][vc0 + 8 + i][vr ^ vkey] = v1[i];
        }

        __syncthreads();   // the ONLY barrier: VT[vb] staged block-wide

        // ---- O += P V (read swizzle key = g<<4, 16B contiguity preserved) ----
        __builtin_amdgcn_s_setprio(1);
#pragma unroll
        for (int ks = 0; ks < 2; ++ks) {
            f16x8 pf = *(const f16x8*)&P[w][l16][ks * 32 + quad * 8];
#pragma unroll
            for (int g = 0; g < 4; ++g) {
                f16x8 vf = *(const f16x8*)&VT[vb][g * 16 + l16][(ks * 32 + quad * 8) ^ (g << 4)];
                oacc[g] = __builtin_amdgcn_mfma_f32_16x16x32_f16(pf, vf, oacc[g], 0, 0, 0);
            }
        }
        __builtin_amdgcn_s_setprio(0);
        // no second barrier: next iter writes VT[vb^1], last read at iter-1,
        // whose readers all passed this iteration's __syncthreads.
    }

    // ---- epilogue: ctx[b, q, h*DK + c] = O / l ----
#pragma unroll
    for (int g = 0; g < 4; ++g)
#pragma unroll
        for (int r = 0; r < 4; ++r) {
            size_t row = (size_t)(q0 + w * 16 + quad * 4 + r);
            ctx[(size_t)b * L_ * D_ + row * D_ + h * DK_ + g * 16 + l16] =
                (f16)(oacc[g][r] / l_r[r]);
        }
}

// ---------------------------------------------------------------------------
// launcher
// ---------------------------------------------------------------------------
extern "C" void kernel_launch(void* const* d_in, const int* in_sizes, int n_in,
                              void* d_out, int out_size, void* d_ws, size_t ws_size,
                              hipStream_t stream)
{
    const float* query = (const float*)d_in[0];
    const float* key   = (const float*)d_in[1];
    const float* value = (const float*)d_in[2];
    const float* pbias = (const float*)d_in[3];
    const float* Wq    = (const float*)d_in[4];
    const float* Wk    = (const float*)d_in[5];
    const float* Wv    = (const float*)d_in[6];
    const float* Wo    = (const float*)d_in[7];
    float* out = (float*)d_out;

    char* ws = (char*)d_ws;
    // workspace layout (needs 64 MiB)
    f16* q16  = (f16*)(ws + 0);           // 4096x1024 halfs = 8 MiB each
    f16* k16  = (f16*)(ws + 8388608);
    f16* v16  = (f16*)(ws + 16777216);
    f16* wq16 = (f16*)(ws + 25165824);    // 1024x1024 halfs = 2 MiB each
    f16* wk16 = (f16*)(ws + 27262976);
    f16* wv16 = (f16*)(ws + 29360128);
    f16* wo16 = (f16*)(ws + 31457280);
    f16* Qs   = (f16*)(ws + 33554432);
    f16* Ks   = (f16*)(ws + 41943040);
    f16* Vs   = (f16*)(ws + 50331648);
    f16* ctx  = (f16*)(ws + 58720256);

    const int ML = B_ * L_;               // 4096
    const int nBig = ML * D_;             // 4,194,304
    const int nW   = D_ * D_;             // 1,048,576

    // batched fp32->fp16 converts: {q,k,v} then {Wq,Wk,Wv,Wo}
    {
        CvtArgs a{};
        a.in[0] = query; a.in[1] = key; a.in[2] = value;
        a.out[0] = q16;  a.out[1] = k16; a.out[2] = v16;
        cvt_f32_f16<<<dim3((nBig / 4 + 255) / 256, 1, 3), 256, 0, stream>>>(a, nBig);
    }
    {
        CvtArgs a{};
        a.in[0] = Wq;   a.in[1] = Wk;   a.in[2] = Wv;   a.in[3] = Wo;
        a.out[0] = wq16; a.out[1] = wk16; a.out[2] = wv16; a.out[3] = wo16;
        cvt_f32_f16<<<dim3((nW / 4 + 255) / 256, 1, 4), 256, 0, stream>>>(a, nW);
    }

    // batched Q/K/V projections: 768 blocks = 3 co-resident blocks/CU
    {
        ProjArgs p{};
        p.A[0] = q16;  p.A[1] = k16;  p.A[2] = v16;
        p.Bm[0] = wq16; p.Bm[1] = wk16; p.Bm[2] = wv16;
        p.C[0] = Qs;   p.C[1] = Ks;   p.C[2] = Vs;
        p.alpha[0] = SCALE_; p.alpha[1] = SCALE_; p.alpha[2] = 1.0f;
        gemm_proj3<<<dim3(D_ / 128, ML / 128, 3), 256, 0, stream>>>(p, ML, D_, D_);
    }

    attn_kernel<<<dim3(B_ * H_ * (L_ / 64)), 256, 0, stream>>>(Qs, Ks, Vs, pbias, ctx);

    gemm_out<<<dim3(D_ / 128, ML / 128), 256, 0, stream>>>(ctx, wo16, out, ML, D_, D_, 1.0f);
}